// Round 2
// baseline (1046.426 us; speedup 1.0000x reference)
//
#include <hip/hip_runtime.h>

// Capsule routing, B=64 R=2048 C=32 O=32 I=16, 3 routing iters.
// Strategy: never materialize u_hat (512 MB). Recompute it in each of 3
// fused passes (W = 128 MB streamed per pass). Logit telescoping:
//   b1 = u.v1 ; b2 = u.(v1+v2)   -> no [B,R,C] logit buffer needed.
// upass<PHASE>: block = 16 b x 16 r, W rows in registers reused over b,
// softmax over C is wave-local (c = lane&31), o-reduction via tiny LDS.

#define Bn 64
#define Rn 2048
#define Cn 32
#define On 32
#define In 16
#define RC 16            // r per upass block
#define NRC (Rn / RC)    // 128 r-chunks
#define GB 16            // b per upass block
#define NBG (Bn / GB)    // 4 b-groups

__device__ __forceinline__ float dot4(float4 a, float4 b) {
    return a.x * b.x + a.y * b.y + a.z * b.z + a.w * b.w;
}

// s_part layout: float4 slot buffer [NRC][Bn][256] (slot = tid, holds 4 k's).
// Slot (tid,k) <-> (c = lane&31, o = 8*wave + 4*(lane>>5) + k).

template <int PHASE>
__global__ __launch_bounds__(256, 2)
void upass(const float* __restrict__ x, const float* __restrict__ W,
           const float* __restrict__ vroute, float* __restrict__ s_part) {
    const int tid   = threadIdx.x;
    const int w     = tid >> 6;
    const int lane  = tid & 63;
    const int c     = lane & 31;
    const int obase = (w << 3) + ((lane >> 5) << 2);
    const int bg    = blockIdx.x;   // [0,4)  fast-varying -> blocks sharing rc adjacent
    const int rc    = blockIdx.y;   // [0,128)
    const int b0    = bg * GB;

    __shared__ float lds_l[128];

    // routing vector slice for this thread's (c, obase..obase+3), all 16 b
    float vr[GB][4];
    if (PHASE > 0) {
#pragma unroll
        for (int b = 0; b < GB; ++b) {
            float4 vv = *(const float4*)(vroute +
                         ((size_t)(b0 + b) * Cn + c) * On + obase);
            vr[b][0] = vv.x; vr[b][1] = vv.y; vr[b][2] = vv.z; vr[b][3] = vv.w;
        }
    }

    float sacc[GB][4];
#pragma unroll
    for (int b = 0; b < GB; ++b)
#pragma unroll
        for (int k = 0; k < 4; ++k) sacc[b][k] = 0.f;

    for (int rr = 0; rr < RC; ++rr) {
        const int r = rc * RC + rr;
        // W[r, c, obase+k, 0:16] -> 16 float4 in registers, reused over 16 b
        float4 wreg[4][4];
        const float4* Wp = (const float4*)W +
                           ((size_t)(r * Cn + c) * On + obase) * 4;
#pragma unroll
        for (int k = 0; k < 4; ++k)
#pragma unroll
            for (int j = 0; j < 4; ++j) wreg[k][j] = Wp[k * 4 + j];

        for (int b = 0; b < GB; ++b) {
            const float4* xp = (const float4*)(x +
                               ((size_t)(b0 + b) * Rn + r) * In);
            float4 x0 = xp[0], x1 = xp[1], x2 = xp[2], x3 = xp[3];
            float u[4];
#pragma unroll
            for (int k = 0; k < 4; ++k)
                u[k] = dot4(wreg[k][0], x0) + dot4(wreg[k][1], x1) +
                       dot4(wreg[k][2], x2) + dot4(wreg[k][3], x3);

            float weight;
            if (PHASE == 0) {
                weight = 1.0f / 32.0f;   // softmax(0) is uniform
            } else {
                // logit partial over this thread's 4 o's
                float lp = u[0] * vr[b][0] + u[1] * vr[b][1] +
                           u[2] * vr[b][2] + u[3] * vr[b][3];
                lp += __shfl_xor(lp, 32, 64);          // 8 o's per wave
                if (lane < 32) lds_l[w * 32 + c] = lp; // cross-wave o-sum
                __syncthreads();
                float l = lds_l[c] + lds_l[32 + c] + lds_l[64 + c] + lds_l[96 + c];
                __syncthreads();
                // softmax over c: lanes 0..31 hold c=0..31 (dup in upper half)
                float m = l;
#pragma unroll
                for (int d = 1; d < 32; d <<= 1)
                    m = fmaxf(m, __shfl_xor(m, d, 64));
                float e = __expf(l - m);
                float ssum = e;
#pragma unroll
                for (int d = 1; d < 32; d <<= 1)
                    ssum += __shfl_xor(ssum, d, 64);
                weight = e / ssum;
            }
#pragma unroll
            for (int k = 0; k < 4; ++k)
                sacc[b][k] = fmaf(weight, u[k], sacc[b][k]);
        }
    }
    // fully-coalesced float4 partial stores
#pragma unroll
    for (int b = 0; b < GB; ++b) {
        float4 v4 = make_float4(sacc[b][0], sacc[b][1], sacc[b][2], sacc[b][3]);
        ((float4*)s_part)[((size_t)rc * Bn + (b0 + b)) * 256 + tid] = v4;
    }
}

// stage 1 reduce: 128 rc-partials -> 16 group-partials. grid (16, 64)
__global__ __launch_bounds__(256)
void reduce1(const float* __restrict__ s_part, float* __restrict__ s2) {
    const int g = blockIdx.x;   // [0,16)
    const int b = blockIdx.y;   // [0,64)
    const int t = threadIdx.x;
    float4 acc = make_float4(0.f, 0.f, 0.f, 0.f);
#pragma unroll
    for (int j = 0; j < 8; ++j) {
        float4 v = ((const float4*)s_part)[((size_t)(g * 8 + j) * Bn + b) * 256 + t];
        acc.x += v.x; acc.y += v.y; acc.z += v.z; acc.w += v.w;
    }
    ((float4*)s2)[((size_t)g * Bn + b) * 256 + t] = acc;
}

// stage 2: finish reduce, apply squash, write v (standard [b,c,o] layout).
// optionally write vsum = v + vprev (for the telescoped logits).
__global__ __launch_bounds__(256)
void squash2(const float* __restrict__ s2, float scale,
             float* __restrict__ vout, const float* __restrict__ vprev,
             float* __restrict__ vsum_out) {
    const int b     = blockIdx.x;   // [0,64)
    const int t     = threadIdx.x;
    const int w     = t >> 6;
    const int lane  = t & 63;
    const int c     = lane & 31;
    const int obase = (w << 3) + ((lane >> 5) << 2);
    __shared__ float lds_n[128];

    float4 acc = make_float4(0.f, 0.f, 0.f, 0.f);
#pragma unroll
    for (int g = 0; g < 16; ++g) {
        float4 v = ((const float4*)s2)[((size_t)g * Bn + b) * 256 + t];
        acc.x += v.x; acc.y += v.y; acc.z += v.z; acc.w += v.w;
    }
    acc.x *= scale; acc.y *= scale; acc.z *= scale; acc.w *= scale;

    // ||s||^2 over o (o spans waves in slot layout -> one LDS exchange)
    float n2p = acc.x * acc.x + acc.y * acc.y + acc.z * acc.z + acc.w * acc.w;
    n2p += __shfl_xor(n2p, 32, 64);
    if (lane < 32) lds_n[w * 32 + c] = n2p;
    __syncthreads();
    float n2 = lds_n[c] + lds_n[32 + c] + lds_n[64 + c] + lds_n[96 + c];
    float norm = sqrtf(n2);
    float f = (n2 / (1.f + n2)) / (norm + 1e-8f);

    float4 vv = make_float4(acc.x * f, acc.y * f, acc.z * f, acc.w * f);
    size_t oidx = (size_t)b * 1024 + (size_t)c * 32 + obase;
    if (vout) *(float4*)(vout + oidx) = vv;
    if (vsum_out) {
        float4 vp = *(const float4*)(vprev + oidx);
        *(float4*)(vsum_out + oidx) =
            make_float4(vv.x + vp.x, vv.y + vp.y, vv.z + vp.z, vv.w + vp.w);
    }
}

extern "C" void kernel_launch(void* const* d_in, const int* in_sizes, int n_in,
                              void* d_out, int out_size, void* d_ws, size_t ws_size,
                              hipStream_t stream) {
    const float* x = (const float*)d_in[0];   // [64,2048,16]
    const float* W = (const float*)d_in[1];   // [2048,32,32,16]
    float* out = (float*)d_out;               // [64,32,32]

    char* ws = (char*)d_ws;
    float* s_part = (float*)ws;                              // 32 MB
    float* s2     = (float*)(ws + (size_t)33554432);         // 4 MB
    float* v1     = (float*)(ws + (size_t)33554432 + 4194304);           // 256 KB
    float* v12    = (float*)(ws + (size_t)33554432 + 4194304 + 262144);  // 256 KB

    dim3 ug(NBG, NRC);          // (4, 128)
    dim3 rg(16, Bn);            // (16, 64)

    // iter 1: uniform coefficients 1/32 applied INSIDE upass<0> (scale=1 here;
    // double-applying it was the round-1 absmax=0.111 bug)
    upass<0><<<ug, 256, 0, stream>>>(x, W, nullptr, s_part);
    reduce1<<<rg, 256, 0, stream>>>(s_part, s2);
    squash2<<<Bn, 256, 0, stream>>>(s2, 1.0f, v1, nullptr, nullptr);

    // iter 2: logits = u.v1 ; need only v12 = v1+v2 afterwards
    upass<1><<<ug, 256, 0, stream>>>(x, W, v1, s_part);
    reduce1<<<rg, 256, 0, stream>>>(s_part, s2);
    squash2<<<Bn, 256, 0, stream>>>(s2, 1.f, nullptr, v1, v12);

    // iter 3: logits = u.(v1+v2) ; output v3
    upass<2><<<ug, 256, 0, stream>>>(x, W, v12, s_part);
    reduce1<<<rg, 256, 0, stream>>>(s_part, s2);
    squash2<<<Bn, 256, 0, stream>>>(s2, 1.f, out, nullptr, nullptr);
}